// Round 1
// baseline (2946.710 us; speedup 1.0000x reference)
//
#include <hip/hip_runtime.h>
#include <math.h>

constexpr int B_ = 2, S_ = 2048, D_ = 2048, NH_ = 16, NKV_ = 4, HD_ = 128;
constexpr int EQKV_ = (NH_ + 2 * NKV_) * HD_;   // 3072
constexpr int M_ = B_ * S_;                     // 4096
constexpr float EPS_ = 1e-6f;
constexpr float QSCALE_ = 0.08838834764831845f; // 1/sqrt(HD)

// ---------------- K1/K4: C[m,n] = sum_k A[m,k] * W[n,k] (fp32 NT) ----------
__global__ __launch_bounds__(256) void gemm_nt(
    const float* __restrict__ A, const float* __restrict__ W,
    float* __restrict__ C, int M, int N, int K)
{
    __shared__ float As[16][65];
    __shared__ float Ws[16][65];
    const int tx = threadIdx.x & 15, ty = threadIdx.x >> 4;
    const int m0 = blockIdx.y * 64, n0 = blockIdx.x * 64;
    const int lk = threadIdx.x & 15, lm = threadIdx.x >> 4;
    float acc[4][4] = {};
    for (int k0 = 0; k0 < K; k0 += 16) {
#pragma unroll
        for (int i = 0; i < 4; ++i) {
            As[lk][lm + 16 * i] = A[(size_t)(m0 + lm + 16 * i) * K + (k0 + lk)];
            Ws[lk][lm + 16 * i] = W[(size_t)(n0 + lm + 16 * i) * K + (k0 + lk)];
        }
        __syncthreads();
#pragma unroll
        for (int k = 0; k < 16; ++k) {
            float a[4], w[4];
#pragma unroll
            for (int i = 0; i < 4; ++i) a[i] = As[k][ty * 4 + i];
#pragma unroll
            for (int j = 0; j < 4; ++j) w[j] = Ws[k][tx * 4 + j];
#pragma unroll
            for (int i = 0; i < 4; ++i)
#pragma unroll
                for (int j = 0; j < 4; ++j)
                    acc[i][j] = fmaf(a[i], w[j], acc[i][j]);
        }
        __syncthreads();
    }
#pragma unroll
    for (int i = 0; i < 4; ++i)
#pragma unroll
        for (int j = 0; j < 4; ++j)
            C[(size_t)(m0 + ty * 4 + i) * N + (n0 + tx * 4 + j)] = acc[i][j];
}

// ------------- K2: RMSNorm + RoPE + scale + transpose to (b,h,s,d) --------
// grid = (B*S, NH+2*NKV), block = 128 (one thread per d)
__global__ __launch_bounds__(128) void norm_rope(
    const float* __restrict__ qkv, const float* __restrict__ freqs,
    const float* __restrict__ qw, const float* __restrict__ kw,
    float* __restrict__ qo, float* __restrict__ ko, float* __restrict__ vo)
{
    const int bs = blockIdx.x;          // b*S + s
    const int head = blockIdx.y;        // 0..23: [0,16)=q, [16,20)=k, [20,24)=v
    const int d = threadIdx.x;
    const int b = bs >> 11, s = bs & (S_ - 1);
    const float x = qkv[(size_t)bs * EQKV_ + head * HD_ + d];

    if (head >= NH_ + NKV_) {           // V: plain copy to (b,kvh,s,d)
        const int vh = head - (NH_ + NKV_);
        vo[((size_t)(b * NKV_ + vh) * S_ + s) * HD_ + d] = x;
        return;
    }
    __shared__ float wsum[2];
    float sq = x * x;
#pragma unroll
    for (int off = 1; off < 64; off <<= 1) sq += __shfl_xor(sq, off);
    if ((threadIdx.x & 63) == 0) wsum[threadIdx.x >> 6] = sq;
    __syncthreads();
    const float rs = rsqrtf((wsum[0] + wsum[1]) * (1.0f / HD_) + EPS_);
    const bool isq = head < NH_;
    const float w = isq ? qw[d] : kw[d];
    const float xn = x * rs * w;
    // RoPE on interleaved pairs (x[2p], x[2p+1]); freqs_cis[s][p][0/1]
    const float other = __shfl_xor(xn, 1);
    const float fr = freqs[s * HD_ + (d & ~1)];
    const float fi = freqs[s * HD_ + (d & ~1) + 1];
    float out = (d & 1) ? fmaf(xn, fr, other * fi)    // odd: xi*fr + xr*fi
                        : fmaf(xn, fr, -other * fi);  // even: xr*fr - xi*fi
    if (isq) {
        out *= QSCALE_;  // fold 1/sqrt(HD) into q
        qo[((size_t)(b * NH_ + head) * S_ + s) * HD_ + d] = out;
    } else {
        const int kh = head - NH_;
        ko[((size_t)(b * NKV_ + kh) * S_ + s) * HD_ + d] = out;
    }
}

// ------------- K3: causal flash attention, fp32, online softmax -----------
// grid = (S/32, NH, B), block = 256. Q tile 32x128, KV tiles 64x128.
__global__ __launch_bounds__(256) void flash_attn(
    const float* __restrict__ Q,   // (B,NH,S,HD), q pre-scaled
    const float* __restrict__ Kt,  // (B,NKV,S,HD)
    const float* __restrict__ Vt,  // (B,NKV,S,HD)
    float* __restrict__ Y)         // (B,S,NH*HD)
{
    __shared__ float Qs[32][132];   // pad 132: conflict-free b128 reads
    __shared__ float KVs[64][132];  // K tile, then V tile
    __shared__ float Ps[32][65];    // probabilities

    const int qt = blockIdx.x, h = blockIdx.y, b = blockIdx.z;
    const int kvh = h >> 2;         // GQA: rep = NH/NKV = 4
    const int q0 = qt * 32;
    const int t = threadIdx.x;
    const int tx = t & 15, ty = t >> 4;
    const int r0 = ty * 2;          // 2 query rows per thread

    const float* qbase = Q + ((size_t)(b * NH_ + h) * S_ + q0) * HD_;
    const float* kbase = Kt + ((size_t)(b * NKV_ + kvh) * S_) * HD_;
    const float* vbase = Vt + ((size_t)(b * NKV_ + kvh) * S_) * HD_;

#pragma unroll
    for (int i = 0; i < 4; ++i) {   // load Q tile: 1024 float4s
        int idx = t + 256 * i;
        int r = idx >> 5, c4 = (idx & 31) * 4;
        *(float4*)&Qs[r][c4] = *(const float4*)&qbase[(size_t)r * HD_ + c4];
    }

    float m_[2] = {-INFINITY, -INFINITY};
    float l_[2] = {0.f, 0.f};
    float o_[2][8] = {};

    const int ntiles = (q0 + 31) / 64 + 1;
    for (int tk = 0; tk < ntiles; ++tk) {
        const int k0 = tk * 64;
        __syncthreads();            // prev PV done with KVs/Ps
#pragma unroll
        for (int i = 0; i < 8; ++i) {  // load K tile: 2048 float4s
            int idx = t + 256 * i;
            int r = idx >> 5, c4 = (idx & 31) * 4;
            *(float4*)&KVs[r][c4] = *(const float4*)&kbase[(size_t)(k0 + r) * HD_ + c4];
        }
        __syncthreads();
        // scores: rows r0+i, cols tx+16*j
        float sc[2][4] = {};
        for (int dd = 0; dd < HD_; dd += 4) {
            float4 q4[2], k4[4];
#pragma unroll
            for (int i = 0; i < 2; ++i) q4[i] = *(const float4*)&Qs[r0 + i][dd];
#pragma unroll
            for (int j = 0; j < 4; ++j) k4[j] = *(const float4*)&KVs[tx + 16 * j][dd];
#pragma unroll
            for (int i = 0; i < 2; ++i)
#pragma unroll
                for (int j = 0; j < 4; ++j) {
                    sc[i][j] = fmaf(q4[i].x, k4[j].x, sc[i][j]);
                    sc[i][j] = fmaf(q4[i].y, k4[j].y, sc[i][j]);
                    sc[i][j] = fmaf(q4[i].z, k4[j].z, sc[i][j]);
                    sc[i][j] = fmaf(q4[i].w, k4[j].w, sc[i][j]);
                }
        }
        // causal mask
#pragma unroll
        for (int i = 0; i < 2; ++i)
#pragma unroll
            for (int j = 0; j < 4; ++j)
                if (k0 + tx + 16 * j > q0 + r0 + i) sc[i][j] = -INFINITY;
        // online softmax; row stats butterfly over the 16 tx lanes (in-wave)
#pragma unroll
        for (int i = 0; i < 2; ++i) {
            float rm = fmaxf(fmaxf(sc[i][0], sc[i][1]), fmaxf(sc[i][2], sc[i][3]));
#pragma unroll
            for (int off = 1; off < 16; off <<= 1) rm = fmaxf(rm, __shfl_xor(rm, off));
            float mn = fmaxf(m_[i], rm);
            float alpha = __expf(m_[i] - mn);   // first tile: exp(-inf)=0
            float rsum = 0.f;
#pragma unroll
            for (int j = 0; j < 4; ++j) {
                sc[i][j] = __expf(sc[i][j] - mn);
                rsum += sc[i][j];
            }
#pragma unroll
            for (int off = 1; off < 16; off <<= 1) rsum += __shfl_xor(rsum, off);
            l_[i] = l_[i] * alpha + rsum;
            m_[i] = mn;
#pragma unroll
            for (int j = 0; j < 8; ++j) o_[i][j] *= alpha;
#pragma unroll
            for (int j = 0; j < 4; ++j) Ps[r0 + i][tx + 16 * j] = sc[i][j];
        }
        __syncthreads();            // scores done reading KVs; Ps visible
#pragma unroll
        for (int i = 0; i < 8; ++i) {  // load V tile into KVs
            int idx = t + 256 * i;
            int r = idx >> 5, c4 = (idx & 31) * 4;
            *(float4*)&KVs[r][c4] = *(const float4*)&vbase[(size_t)(k0 + r) * HD_ + c4];
        }
        __syncthreads();
        // PV: o[r][tx+16j] += sum_kk P[r][kk] * V[kk][tx+16j]
        for (int kk = 0; kk < 64; ++kk) {
            float p0 = Ps[r0][kk], p1 = Ps[r0 + 1][kk];
#pragma unroll
            for (int j = 0; j < 8; ++j) {
                float v = KVs[kk][tx + 16 * j];
                o_[0][j] = fmaf(p0, v, o_[0][j]);
                o_[1][j] = fmaf(p1, v, o_[1][j]);
            }
        }
    }
#pragma unroll
    for (int i = 0; i < 2; ++i) {
        float inv = 1.0f / l_[i];
#pragma unroll
        for (int j = 0; j < 8; ++j)
            Y[(size_t)(b * S_ + q0 + r0 + i) * (NH_ * HD_) + h * HD_ + tx + 16 * j] =
                o_[i][j] * inv;
    }
}

extern "C" void kernel_launch(void* const* d_in, const int* in_sizes, int n_in,
                              void* d_out, int out_size, void* d_ws, size_t ws_size,
                              hipStream_t stream)
{
    const float* x     = (const float*)d_in[0];
    const float* freqs = (const float*)d_in[1];
    const float* wqkv  = (const float*)d_in[2];
    const float* wo    = (const float*)d_in[3];
    const float* qw    = (const float*)d_in[4];
    const float* kw    = (const float*)d_in[5];
    float* out = (float*)d_out;

    // workspace layout (fp32): qkv | qrot | krot | vt ; y reuses qkv
    float* qkv  = (float*)d_ws;                          // 4096*3072
    float* qrot = qkv + (size_t)M_ * EQKV_;              // (B,NH,S,HD)
    float* krot = qrot + (size_t)B_ * NH_ * S_ * HD_;    // (B,NKV,S,HD)
    float* vt   = krot + (size_t)B_ * NKV_ * S_ * HD_;   // (B,NKV,S,HD)
    float* y    = qkv;                                   // (B,S,NH*HD), reuse

    // K1: qkv[m,e] = sum_d x[m,d] * wqkv[e,d]
    gemm_nt<<<dim3(EQKV_ / 64, M_ / 64), 256, 0, stream>>>(x, wqkv, qkv, M_, EQKV_, D_);
    // K2: rmsnorm + rope + transpose (+1/sqrt(HD) folded into q)
    norm_rope<<<dim3(M_, NH_ + 2 * NKV_), 128, 0, stream>>>(qkv, freqs, qw, kw,
                                                            qrot, krot, vt);
    // K3: causal flash attention
    flash_attn<<<dim3(S_ / 32, NH_, B_), 256, 0, stream>>>(qrot, krot, vt, y);
    // K4: out[m,d] = sum_e y[m,e] * wo[d,e]
    gemm_nt<<<dim3(D_ / 64, M_ / 64), 256, 0, stream>>>(y, wo, out, M_, D_, NH_ * HD_);
}

// Round 3
// 1471.904 us; speedup vs baseline: 2.0020x; 2.0020x over previous
//
#include <hip/hip_runtime.h>
#include <math.h>

constexpr int B_ = 2, S_ = 2048, D_ = 2048, NH_ = 16, NKV_ = 4, HD_ = 128;
constexpr int EQKV_ = (NH_ + 2 * NKV_) * HD_;   // 3072
constexpr int M_ = B_ * S_;                     // 4096
constexpr float EPS_ = 1e-6f;
constexpr float QSCALE_ = 0.08838834764831845f; // 1/sqrt(HD)

typedef __attribute__((ext_vector_type(8))) short bf16x8;
typedef __attribute__((ext_vector_type(4))) float f32x4;
typedef __attribute__((address_space(1))) unsigned int gu32;
typedef __attribute__((address_space(3))) unsigned int lu32;

__device__ inline ushort f2bf(float f) {   // RNE fp32->bf16 (finite inputs)
    unsigned u = __float_as_uint(f);
    return (ushort)((u + 0x7FFF + ((u >> 16) & 1)) >> 16);
}

// ---------------- pack: fp32 -> bf16, float4 per thread --------------------
__global__ __launch_bounds__(256) void pack_bf16(
    const float* __restrict__ in, ushort* __restrict__ out, int n4)
{
    int i = blockIdx.x * 256 + threadIdx.x;
    if (i >= n4) return;
    float4 f = ((const float4*)in)[i];
    ushort4 u;
    u.x = f2bf(f.x); u.y = f2bf(f.y); u.z = f2bf(f.z); u.w = f2bf(f.w);
    ((ushort4*)out)[i] = u;
}

// ------- K1/K4: C[m,n] = sum_k A[m,k]*W[n,k], bf16 MFMA (m97 structure) ----
// block 256 = 4 waves in 2x2; 128x128 C-tile; BK=32; 16x16x32 bf16 MFMA
__global__ __launch_bounds__(256) void gemm_nt_bf16(
    const ushort* __restrict__ A, const ushort* __restrict__ W,
    float* __restrict__ C, int M, int N, int K)
{
    __shared__ ushort As[128 * 32];
    __shared__ ushort Bs[128 * 32];
    const int t = threadIdx.x;
    const int wave = t >> 6, lane = t & 63;
    const int m0 = blockIdx.y * 128, n0 = blockIdx.x * 128;
    const int wm = (wave >> 1) * 64, wn = (wave & 1) * 64;
    const int lrow = lane & 15, lquad = lane >> 4;

    f32x4 acc[4][4];
#pragma unroll
    for (int i = 0; i < 4; ++i)
#pragma unroll
        for (int j = 0; j < 4; ++j) acc[i][j] = (f32x4){0.f, 0.f, 0.f, 0.f};

    for (int k0 = 0; k0 < K; k0 += 32) {
        __syncthreads();   // prior ds_reads done before restage
#pragma unroll
        for (int i = 0; i < 2; ++i) {
            int chunk = t + 256 * i;          // 16B chunk id, 0..511
            int row = chunk >> 2, seg = chunk & 3;
            int ubase = (wave * 64 + 256 * i) * 8;  // wave-uniform LDS base (ushorts)
            __builtin_amdgcn_global_load_lds(
                (const gu32*)(A + (size_t)(m0 + row) * K + k0 + seg * 8),
                (lu32*)(As + ubase), 16, 0, 0);
            __builtin_amdgcn_global_load_lds(
                (const gu32*)(W + (size_t)(n0 + row) * K + k0 + seg * 8),
                (lu32*)(Bs + ubase), 16, 0, 0);
        }
        __syncthreads();   // vmcnt(0) drained here by compiler

        bf16x8 af[4], bf[4];
#pragma unroll
        for (int i = 0; i < 4; ++i) {
            af[i] = *(const bf16x8*)(As + (wm + i * 16 + lrow) * 32 + lquad * 8);
            bf[i] = *(const bf16x8*)(Bs + (wn + i * 16 + lrow) * 32 + lquad * 8);
        }
#pragma unroll
        for (int i = 0; i < 4; ++i)
#pragma unroll
            for (int j = 0; j < 4; ++j)
                acc[i][j] = __builtin_amdgcn_mfma_f32_16x16x32_bf16(
                    af[i], bf[j], acc[i][j], 0, 0, 0);
    }
    // C/D layout: col = lane&15, row = (lane>>4)*4 + reg  [m89/m91 verified]
#pragma unroll
    for (int i = 0; i < 4; ++i)
#pragma unroll
        for (int j = 0; j < 4; ++j) {
            float* cp = C + (size_t)(m0 + wm + i * 16 + lquad * 4) * N
                          + n0 + wn + j * 16 + lrow;
#pragma unroll
            for (int r = 0; r < 4; ++r) cp[(size_t)r * N] = acc[i][j][r];
        }
}

// ------------- K2: RMSNorm + RoPE + scale + transpose to (b,h,s,d) --------
__global__ __launch_bounds__(128) void norm_rope(
    const float* __restrict__ qkv, const float* __restrict__ freqs,
    const float* __restrict__ qw, const float* __restrict__ kw,
    float* __restrict__ qo, float* __restrict__ ko, float* __restrict__ vo)
{
    const int bs = blockIdx.x;
    const int head = blockIdx.y;        // [0,16)=q, [16,20)=k, [20,24)=v
    const int d = threadIdx.x;
    const int b = bs >> 11, s = bs & (S_ - 1);
    const float x = qkv[(size_t)bs * EQKV_ + head * HD_ + d];

    if (head >= NH_ + NKV_) {
        const int vh = head - (NH_ + NKV_);
        vo[((size_t)(b * NKV_ + vh) * S_ + s) * HD_ + d] = x;
        return;
    }
    __shared__ float wsum[2];
    float sq = x * x;
#pragma unroll
    for (int off = 1; off < 64; off <<= 1) sq += __shfl_xor(sq, off);
    if ((threadIdx.x & 63) == 0) wsum[threadIdx.x >> 6] = sq;
    __syncthreads();
    const float rs = rsqrtf((wsum[0] + wsum[1]) * (1.0f / HD_) + EPS_);
    const bool isq = head < NH_;
    const float w = isq ? qw[d] : kw[d];
    const float xn = x * rs * w;
    const float other = __shfl_xor(xn, 1);
    const float fr = freqs[s * HD_ + (d & ~1)];
    const float fi = freqs[s * HD_ + (d & ~1) + 1];
    float out = (d & 1) ? fmaf(xn, fr, other * fi)
                        : fmaf(xn, fr, -other * fi);
    if (isq) {
        out *= QSCALE_;
        qo[((size_t)(b * NH_ + head) * S_ + s) * HD_ + d] = out;
    } else {
        const int kh = head - NH_;
        ko[((size_t)(b * NKV_ + kh) * S_ + s) * HD_ + d] = out;
    }
}

// ------------- K3: causal flash attention, fp32, online softmax -----------
__global__ __launch_bounds__(256) void flash_attn(
    const float* __restrict__ Q, const float* __restrict__ Kt,
    const float* __restrict__ Vt,
    ushort* __restrict__ Y)        // (B,S,NH*HD) bf16 for the MFMA out-proj
{
    __shared__ float Qs[32][132];
    __shared__ float KVs[64][132];
    __shared__ float Ps[32][65];

    const int qt = blockIdx.x, h = blockIdx.y, b = blockIdx.z;
    const int kvh = h >> 2;
    const int q0 = qt * 32;
    const int t = threadIdx.x;
    const int tx = t & 15, ty = t >> 4;
    const int r0 = ty * 2;

    const float* qbase = Q + ((size_t)(b * NH_ + h) * S_ + q0) * HD_;
    const float* kbase = Kt + ((size_t)(b * NKV_ + kvh) * S_) * HD_;
    const float* vbase = Vt + ((size_t)(b * NKV_ + kvh) * S_) * HD_;

#pragma unroll
    for (int i = 0; i < 4; ++i) {
        int idx = t + 256 * i;
        int r = idx >> 5, c4 = (idx & 31) * 4;
        *(float4*)&Qs[r][c4] = *(const float4*)&qbase[(size_t)r * HD_ + c4];
    }

    float m_[2] = {-INFINITY, -INFINITY};
    float l_[2] = {0.f, 0.f};
    float o_[2][8] = {};

    const int ntiles = (q0 + 31) / 64 + 1;
    for (int tk = 0; tk < ntiles; ++tk) {
        const int k0 = tk * 64;
        __syncthreads();
#pragma unroll
        for (int i = 0; i < 8; ++i) {
            int idx = t + 256 * i;
            int r = idx >> 5, c4 = (idx & 31) * 4;
            *(float4*)&KVs[r][c4] = *(const float4*)&kbase[(size_t)(k0 + r) * HD_ + c4];
        }
        __syncthreads();
        float sc[2][4] = {};
        for (int dd = 0; dd < HD_; dd += 4) {
            float4 q4[2], k4[4];
#pragma unroll
            for (int i = 0; i < 2; ++i) q4[i] = *(const float4*)&Qs[r0 + i][dd];
#pragma unroll
            for (int j = 0; j < 4; ++j) k4[j] = *(const float4*)&KVs[tx + 16 * j][dd];
#pragma unroll
            for (int i = 0; i < 2; ++i)
#pragma unroll
                for (int j = 0; j < 4; ++j) {
                    sc[i][j] = fmaf(q4[i].x, k4[j].x, sc[i][j]);
                    sc[i][j] = fmaf(q4[i].y, k4[j].y, sc[i][j]);
                    sc[i][j] = fmaf(q4[i].z, k4[j].z, sc[i][j]);
                    sc[i][j] = fmaf(q4[i].w, k4[j].w, sc[i][j]);
                }
        }
#pragma unroll
        for (int i = 0; i < 2; ++i)
#pragma unroll
            for (int j = 0; j < 4; ++j)
                if (k0 + tx + 16 * j > q0 + r0 + i) sc[i][j] = -INFINITY;
#pragma unroll
        for (int i = 0; i < 2; ++i) {
            float rm = fmaxf(fmaxf(sc[i][0], sc[i][1]), fmaxf(sc[i][2], sc[i][3]));
#pragma unroll
            for (int off = 1; off < 16; off <<= 1) rm = fmaxf(rm, __shfl_xor(rm, off));
            float mn = fmaxf(m_[i], rm);
            float alpha = __expf(m_[i] - mn);
            float rsum = 0.f;
#pragma unroll
            for (int j = 0; j < 4; ++j) {
                sc[i][j] = __expf(sc[i][j] - mn);
                rsum += sc[i][j];
            }
#pragma unroll
            for (int off = 1; off < 16; off <<= 1) rsum += __shfl_xor(rsum, off);
            l_[i] = l_[i] * alpha + rsum;
            m_[i] = mn;
#pragma unroll
            for (int j = 0; j < 8; ++j) o_[i][j] *= alpha;
#pragma unroll
            for (int j = 0; j < 4; ++j) Ps[r0 + i][tx + 16 * j] = sc[i][j];
        }
        __syncthreads();
#pragma unroll
        for (int i = 0; i < 8; ++i) {
            int idx = t + 256 * i;
            int r = idx >> 5, c4 = (idx & 31) * 4;
            *(float4*)&KVs[r][c4] = *(const float4*)&vbase[(size_t)(k0 + r) * HD_ + c4];
        }
        __syncthreads();
        for (int kk = 0; kk < 64; ++kk) {
            float p0 = Ps[r0][kk], p1 = Ps[r0 + 1][kk];
#pragma unroll
            for (int j = 0; j < 8; ++j) {
                float v = KVs[kk][tx + 16 * j];
                o_[0][j] = fmaf(p0, v, o_[0][j]);
                o_[1][j] = fmaf(p1, v, o_[1][j]);
            }
        }
    }
#pragma unroll
    for (int i = 0; i < 2; ++i) {
        float inv = 1.0f / l_[i];
#pragma unroll
        for (int j = 0; j < 8; ++j)
            Y[(size_t)(b * S_ + q0 + r0 + i) * (NH_ * HD_) + h * HD_ + tx + 16 * j] =
                f2bf(o_[i][j] * inv);
    }
}

extern "C" void kernel_launch(void* const* d_in, const int* in_sizes, int n_in,
                              void* d_out, int out_size, void* d_ws, size_t ws_size,
                              hipStream_t stream)
{
    const float* x     = (const float*)d_in[0];
    const float* freqs = (const float*)d_in[1];
    const float* wqkv  = (const float*)d_in[2];
    const float* wo    = (const float*)d_in[3];
    const float* qw    = (const float*)d_in[4];
    const float* kw    = (const float*)d_in[5];
    float* out = (float*)d_out;

    // ws layout (100.7 MB, with overlays):
    //   qkv fp32 [12.58M f = 25.17M u16] | qrot [8.39M f] | krot | vt
    //   xbf[8.39M u16]+wqkvbf[6.29M u16] overlay qrot (14.68M <= 16.78M u16 ok);
    //   ybf[8.39M u16]+wobf[4.19M u16] overlay qkv (12.58M <= 25.17M u16 ok).
    //   R2 BUG (fixed): wobf was at 4.19M u16, inside ybf's 8.39M footprint ->
    //   flash_attn overwrote wo with y; out became <y_m, y_{2048+d}> (absmax~2048).
    float* qkv  = (float*)d_ws;
    float* qrot = qkv + (size_t)M_ * EQKV_;
    float* krot = qrot + (size_t)B_ * NH_ * S_ * HD_;
    float* vt   = krot + (size_t)B_ * NKV_ * S_ * HD_;

    ushort* xbf    = (ushort*)qrot;                           // 8.39M u16
    ushort* wqkvbf = (ushort*)qrot + (size_t)M_ * D_;         // 6.29M u16
    ushort* ybf    = (ushort*)qkv;                            // 8.39M u16
    ushort* wobf   = (ushort*)qkv + (size_t)M_ * NH_ * HD_;   // after ybf (fixed)

    pack_bf16<<<(M_ * D_ / 4 + 255) / 256, 256, 0, stream>>>(x, xbf, M_ * D_ / 4);
    pack_bf16<<<(EQKV_ * D_ / 4 + 255) / 256, 256, 0, stream>>>(wqkv, wqkvbf,
                                                                EQKV_ * D_ / 4);
    // K1: qkv = x @ wqkv^T  (bf16 MFMA)
    gemm_nt_bf16<<<dim3(EQKV_ / 128, M_ / 128), 256, 0, stream>>>(
        xbf, wqkvbf, qkv, M_, EQKV_, D_);
    // K2: rmsnorm + rope + transpose (overwrites xbf/wqkvbf region — K1 done)
    norm_rope<<<dim3(M_, NH_ + 2 * NKV_), 128, 0, stream>>>(qkv, freqs, qw, kw,
                                                            qrot, krot, vt);
    // pack wo now that the qkv region is dead
    pack_bf16<<<(D_ * NH_ * HD_ / 4 + 255) / 256, 256, 0, stream>>>(
        wo, wobf, D_ * NH_ * HD_ / 4);
    // K3: causal flash attention -> ybf (bf16, overlays consumed qkv)
    flash_attn<<<dim3(S_ / 32, NH_, B_), 256, 0, stream>>>(qrot, krot, vt, ybf);
    // K4: out = y @ wo^T  (bf16 MFMA)
    gemm_nt_bf16<<<dim3(D_ / 128, M_ / 128), 256, 0, stream>>>(
        ybf, wobf, out, M_, D_, NH_ * HD_);
}

// Round 4
// 480.124 us; speedup vs baseline: 6.1374x; 3.0657x over previous
//
#include <hip/hip_runtime.h>
#include <math.h>

constexpr int B_ = 2, S_ = 2048, D_ = 2048, NH_ = 16, NKV_ = 4, HD_ = 128;
constexpr int EQKV_ = (NH_ + 2 * NKV_) * HD_;   // 3072
constexpr int M_ = B_ * S_;                     // 4096
constexpr float EPS_ = 1e-6f;
constexpr float QSCALE_ = 0.08838834764831845f; // 1/sqrt(HD)

typedef __attribute__((ext_vector_type(8))) short bf16x8;
typedef __attribute__((ext_vector_type(4))) float f32x4;
typedef __attribute__((address_space(1))) unsigned int gu32;
typedef __attribute__((address_space(3))) unsigned int lu32;

__device__ inline ushort f2bf(float f) {   // RNE fp32->bf16 (finite inputs)
    unsigned u = __float_as_uint(f);
    return (ushort)((u + 0x7FFF + ((u >> 16) & 1)) >> 16);
}

// ---------------- pack: fp32 -> bf16, float4 per thread --------------------
__global__ __launch_bounds__(256) void pack_bf16(
    const float* __restrict__ in, ushort* __restrict__ out, int n4)
{
    int i = blockIdx.x * 256 + threadIdx.x;
    if (i >= n4) return;
    float4 f = ((const float4*)in)[i];
    ushort4 u;
    u.x = f2bf(f.x); u.y = f2bf(f.y); u.z = f2bf(f.z); u.w = f2bf(f.w);
    ((ushort4*)out)[i] = u;
}

// ------- K1/K4: C[m,n] = sum_k A[m,k]*W[n,k], bf16 MFMA (m97 structure) ----
__global__ __launch_bounds__(256) void gemm_nt_bf16(
    const ushort* __restrict__ A, const ushort* __restrict__ W,
    float* __restrict__ C, int M, int N, int K)
{
    __shared__ ushort As[128 * 32];
    __shared__ ushort Bs[128 * 32];
    const int t = threadIdx.x;
    const int wave = t >> 6, lane = t & 63;
    const int m0 = blockIdx.y * 128, n0 = blockIdx.x * 128;
    const int wm = (wave >> 1) * 64, wn = (wave & 1) * 64;
    const int lrow = lane & 15, lquad = lane >> 4;

    f32x4 acc[4][4];
#pragma unroll
    for (int i = 0; i < 4; ++i)
#pragma unroll
        for (int j = 0; j < 4; ++j) acc[i][j] = (f32x4){0.f, 0.f, 0.f, 0.f};

    for (int k0 = 0; k0 < K; k0 += 32) {
        __syncthreads();
#pragma unroll
        for (int i = 0; i < 2; ++i) {
            int chunk = t + 256 * i;
            int row = chunk >> 2, seg = chunk & 3;
            int ubase = (wave * 64 + 256 * i) * 8;
            __builtin_amdgcn_global_load_lds(
                (const gu32*)(A + (size_t)(m0 + row) * K + k0 + seg * 8),
                (lu32*)(As + ubase), 16, 0, 0);
            __builtin_amdgcn_global_load_lds(
                (const gu32*)(W + (size_t)(n0 + row) * K + k0 + seg * 8),
                (lu32*)(Bs + ubase), 16, 0, 0);
        }
        __syncthreads();

        bf16x8 af[4], bf[4];
#pragma unroll
        for (int i = 0; i < 4; ++i) {
            af[i] = *(const bf16x8*)(As + (wm + i * 16 + lrow) * 32 + lquad * 8);
            bf[i] = *(const bf16x8*)(Bs + (wn + i * 16 + lrow) * 32 + lquad * 8);
        }
#pragma unroll
        for (int i = 0; i < 4; ++i)
#pragma unroll
            for (int j = 0; j < 4; ++j)
                acc[i][j] = __builtin_amdgcn_mfma_f32_16x16x32_bf16(
                    af[i], bf[j], acc[i][j], 0, 0, 0);
    }
#pragma unroll
    for (int i = 0; i < 4; ++i)
#pragma unroll
        for (int j = 0; j < 4; ++j) {
            float* cp = C + (size_t)(m0 + wm + i * 16 + lquad * 4) * N
                          + n0 + wn + j * 16 + lrow;
#pragma unroll
            for (int r = 0; r < 4; ++r) cp[(size_t)r * N] = acc[i][j][r];
        }
}

// ------ K2: RMSNorm + RoPE + scale + bf16 + transpose; V emitted as V^T ----
// qo (b,NH,s,d) bf16 ; ko (b,NKV,s,d) bf16 ; vo (b,NKV,d,s) bf16 TRANSPOSED
__global__ __launch_bounds__(128) void norm_rope(
    const float* __restrict__ qkv, const float* __restrict__ freqs,
    const float* __restrict__ qw, const float* __restrict__ kw,
    ushort* __restrict__ qo, ushort* __restrict__ ko, ushort* __restrict__ vo)
{
    const int bs = blockIdx.x;
    const int head = blockIdx.y;        // [0,16)=q, [16,20)=k, [20,24)=v
    const int d = threadIdx.x;
    const int b = bs >> 11, s = bs & (S_ - 1);
    const float x = qkv[(size_t)bs * EQKV_ + head * HD_ + d];

    if (head >= NH_ + NKV_) {           // V: bf16 + transpose to (b,kvh,d,s)
        const int vh = head - (NH_ + NKV_);
        vo[((size_t)(b * NKV_ + vh) * HD_ + d) * S_ + s] = f2bf(x);
        return;
    }
    __shared__ float wsum[2];
    float sq = x * x;
#pragma unroll
    for (int off = 1; off < 64; off <<= 1) sq += __shfl_xor(sq, off);
    if ((threadIdx.x & 63) == 0) wsum[threadIdx.x >> 6] = sq;
    __syncthreads();
    const float rs = rsqrtf((wsum[0] + wsum[1]) * (1.0f / HD_) + EPS_);
    const bool isq = head < NH_;
    const float w = isq ? qw[d] : kw[d];
    const float xn = x * rs * w;
    const float other = __shfl_xor(xn, 1);
    const float fr = freqs[s * HD_ + (d & ~1)];
    const float fi = freqs[s * HD_ + (d & ~1) + 1];
    float out = (d & 1) ? fmaf(xn, fr, other * fi)
                        : fmaf(xn, fr, -other * fi);
    if (isq) {
        out *= QSCALE_;
        qo[((size_t)(b * NH_ + head) * S_ + s) * HD_ + d] = f2bf(out);
    } else {
        const int kh = head - NH_;
        ko[((size_t)(b * NKV_ + kh) * S_ + s) * HD_ + d] = f2bf(out);
    }
}

// ------------- K3: causal flash attention, bf16 MFMA ----------------------
// grid (32, NH, B), block 256 = 4 waves. Q tile 64 (16 q-rows/wave), KV 64.
__global__ __launch_bounds__(256) void flash_attn_mfma(
    const ushort* __restrict__ Q,   // (B,NH,S,HD) bf16, pre-scaled by 1/sqrt(HD)
    const ushort* __restrict__ K,   // (B,NKV,S,HD) bf16
    const ushort* __restrict__ V,   // (B,NKV,HD,S) bf16 -- transposed
    ushort* __restrict__ Y)         // (B,S,NH*HD) bf16
{
    __shared__ ushort Ks[4 * 64 * 32];   // [kstep][krow][32]  16 KB
    __shared__ ushort Vs[2 * 128 * 32];  // [kkstep][d][32]    16 KB
    __shared__ ushort Ps[4 * 16 * 72];   // per-wave P, pad 72  9 KB

    const int t = threadIdx.x, w = t >> 6, lane = t & 63;
    const int lx = lane & 15, quad = lane >> 4;
    const int h = blockIdx.y, b = blockIdx.z;
    const int qt = (int)gridDim.x - 1 - (int)blockIdx.x;  // heavy blocks first
    const int q0 = qt * 64;
    const int kvh = h >> 2;
    const int srow = lane >> 2, sseg = lane & 3;          // staging row/seg

    const ushort* qb = Q + ((size_t)(b * NH_ + h) * S_ + q0) * HD_;
    const ushort* kb = K + ((size_t)(b * NKV_ + kvh) * S_) * HD_;
    const ushort* vb = V + ((size_t)(b * NKV_ + kvh) * HD_) * S_;

    // Q A-fragments: rows w*16+lx, k = ks*32 + quad*8 .. +8  (kept in regs)
    bf16x8 aq[4];
#pragma unroll
    for (int ks = 0; ks < 4; ++ks)
        aq[ks] = *(const bf16x8*)(qb + (size_t)(w * 16 + lx) * HD_ + ks * 32 + quad * 8);

    f32x4 o[8];
#pragma unroll
    for (int j = 0; j < 8; ++j) o[j] = (f32x4){0.f, 0.f, 0.f, 0.f};
    float mrow[4] = {-INFINITY, -INFINITY, -INFINITY, -INFINITY};
    float lrow[4] = {0.f, 0.f, 0.f, 0.f};

    const int ntiles = qt + 1;
    for (int tk = 0; tk < ntiles; ++tk) {
        const int k0 = tk * 64;
        __syncthreads();                 // prior tile's LDS reads done
        // stage K tile: Ks[kstep=i][row][seg*8], lane-linear per wave
#pragma unroll
        for (int i = 0; i < 4; ++i)
            __builtin_amdgcn_global_load_lds(
                (const gu32*)(kb + (size_t)(k0 + w * 16 + srow) * HD_ + i * 32 + sseg * 8),
                (lu32*)(Ks + (i * 2048 + w * 512) + 0) /* + lane*8 u16 implicit */,
                16, 0, 0);
        // stage V^T tile: Vs[kkstep][d][seg*8]; d = half*64 + w*16 + srow
#pragma unroll
        for (int i = 0; i < 4; ++i) {
            int kks = i >> 1, hf = i & 1;
            int dr = hf * 64 + w * 16 + srow;
            __builtin_amdgcn_global_load_lds(
                (const gu32*)(vb + (size_t)dr * S_ + k0 + kks * 32 + sseg * 8),
                (lu32*)(Vs + (kks * 4096 + hf * 2048 + w * 512)),
                16, 0, 0);
        }
        __syncthreads();                 // staged data visible

        // ---- S = Q K^T : wave slab 16q x 64k, C-layout ----
        f32x4 s[4];
#pragma unroll
        for (int j = 0; j < 4; ++j) s[j] = (f32x4){0.f, 0.f, 0.f, 0.f};
#pragma unroll
        for (int ks = 0; ks < 4; ++ks) {
#pragma unroll
            for (int j = 0; j < 4; ++j) {
                bf16x8 bk = *(const bf16x8*)(Ks + ks * 2048 + (j * 16 + lx) * 32 + quad * 8);
                s[j] = __builtin_amdgcn_mfma_f32_16x16x32_bf16(aq[ks], bk, s[j], 0, 0, 0);
            }
        }
        // ---- causal mask + online softmax (rows quad*4+reg, cols lx+16j) --
        const int qrow_base = q0 + w * 16 + quad * 4;
#pragma unroll
        for (int reg = 0; reg < 4; ++reg) {
            const int qrow = qrow_base + reg;
#pragma unroll
            for (int j = 0; j < 4; ++j)
                if (k0 + lx + 16 * j > qrow) s[j][reg] = -INFINITY;
            float rm = fmaxf(fmaxf(s[0][reg], s[1][reg]),
                             fmaxf(s[2][reg], s[3][reg]));
#pragma unroll
            for (int off = 1; off < 16; off <<= 1) rm = fmaxf(rm, __shfl_xor(rm, off));
            const float mn = fmaxf(mrow[reg], rm);
            const float alpha = __expf(mrow[reg] - mn);
            float rsum = 0.f;
            float p[4];
#pragma unroll
            for (int j = 0; j < 4; ++j) {
                p[j] = __expf(s[j][reg] - mn);
                rsum += p[j];
            }
#pragma unroll
            for (int off = 1; off < 16; off <<= 1) rsum += __shfl_xor(rsum, off);
            lrow[reg] = lrow[reg] * alpha + rsum;
            mrow[reg] = mn;
#pragma unroll
            for (int j = 0; j < 8; ++j) o[j][reg] *= alpha;
            // write P (bf16) to this wave's LDS slab
#pragma unroll
            for (int j = 0; j < 4; ++j)
                Ps[w * 1152 + (quad * 4 + reg) * 72 + lx + 16 * j] = f2bf(p[j]);
        }
        // ---- O += P V : P A-frags from LDS, V^T B-frags ----
        bf16x8 ap[2];
#pragma unroll
        for (int ks2 = 0; ks2 < 2; ++ks2)
            ap[ks2] = *(const bf16x8*)(Ps + w * 1152 + lx * 72 + ks2 * 32 + quad * 8);
#pragma unroll
        for (int jd = 0; jd < 8; ++jd) {
#pragma unroll
            for (int ks2 = 0; ks2 < 2; ++ks2) {
                bf16x8 bv = *(const bf16x8*)(Vs + ks2 * 4096 + (jd * 16 + lx) * 32 + quad * 8);
                o[jd] = __builtin_amdgcn_mfma_f32_16x16x32_bf16(ap[ks2], bv, o[jd], 0, 0, 0);
            }
        }
    }
    // ---- epilogue: Y[b, q, h*128 + d] = O / l ----
#pragma unroll
    for (int reg = 0; reg < 4; ++reg) {
        const float inv = 1.0f / lrow[reg];
        const size_t yb = (size_t)(b * S_ + q0 + w * 16 + quad * 4 + reg) * (NH_ * HD_)
                        + h * HD_ + lx;
#pragma unroll
        for (int jd = 0; jd < 8; ++jd)
            Y[yb + jd * 16] = f2bf(o[jd][reg] * inv);
    }
}

extern "C" void kernel_launch(void* const* d_in, const int* in_sizes, int n_in,
                              void* d_out, int out_size, void* d_ws, size_t ws_size,
                              hipStream_t stream)
{
    const float* x     = (const float*)d_in[0];
    const float* freqs = (const float*)d_in[1];
    const float* wqkv  = (const float*)d_in[2];
    const float* wo    = (const float*)d_in[3];
    const float* qw    = (const float*)d_in[4];
    const float* kw    = (const float*)d_in[5];
    float* out = (float*)d_out;

    // ws layout (100,663,296 B total, byte offsets; liveness-checked):
    //   [0..50.33M)      qkv fp32 (K1 out, norm_rope in); later wobf@0 (8.39M)
    //                    + ybf@8.39M (16.78M) after norm_rope consumes qkv
    //   [50.33M..62.91M) wqkvbf (K1 in only); later qbf@50.33M (16.78M)
    //   [67.11M..71.30M) kbf ; [71.30M..75.50M) vtb (transposed V)
    //   [83.89M..100.66M) xbf (K1 in only)
    char* ws = (char*)d_ws;
    float*  qkv    = (float*)ws;
    ushort* wqkvbf = (ushort*)(ws + 50331648);
    ushort* xbf    = (ushort*)(ws + 83886080);
    ushort* qbf    = (ushort*)(ws + 50331648);
    ushort* kbf    = (ushort*)(ws + 67108864);
    ushort* vtb    = (ushort*)(ws + 71303168);
    ushort* wobf   = (ushort*)(ws + 0);
    ushort* ybf    = (ushort*)(ws + 8388608);

    pack_bf16<<<(M_ * D_ / 4 + 255) / 256, 256, 0, stream>>>(x, xbf, M_ * D_ / 4);
    pack_bf16<<<(EQKV_ * D_ / 4 + 255) / 256, 256, 0, stream>>>(wqkv, wqkvbf,
                                                                EQKV_ * D_ / 4);
    // K1: qkv = x @ wqkv^T  (bf16 MFMA, fp32 out)
    gemm_nt_bf16<<<dim3(EQKV_ / 128, M_ / 128), 256, 0, stream>>>(
        xbf, wqkvbf, qkv, M_, EQKV_, D_);
    // K2: rmsnorm + rope -> bf16 q/k + transposed bf16 V (overwrites wqkvbf)
    norm_rope<<<dim3(M_, NH_ + 2 * NKV_), 128, 0, stream>>>(qkv, freqs, qw, kw,
                                                            qbf, kbf, vtb);
    // pack wo into dead qkv region
    pack_bf16<<<(D_ * NH_ * HD_ / 4 + 255) / 256, 256, 0, stream>>>(
        wo, wobf, D_ * NH_ * HD_ / 4);
    // K3: MFMA flash attention -> ybf
    flash_attn_mfma<<<dim3(S_ / 64, NH_, B_), 256, 0, stream>>>(qbf, kbf, vtb, ybf);
    // K4: out = y @ wo^T  (bf16 MFMA)
    gemm_nt_bf16<<<dim3(D_ / 128, M_ / 128), 256, 0, stream>>>(
        ybf, wobf, out, M_, D_, NH_ * HD_);
}